// Round 1
// baseline (237.299 us; speedup 1.0000x reference)
//
#include <hip/hip_runtime.h>
#include <math.h>

#define BB 8
#define NN 2000
#define CC 81
#define NPAD 2048
#define MAXI 100
#define HH 512
#define WW 512

// ---------------------------------------------------------------------------
// Kernel A: per-proposal class argmax, delta refine, validity.
// One wave (64 lanes) per proposal: coalesced prob reads, shuffle argmax.
// ---------------------------------------------------------------------------
__global__ void k_refine(const float* __restrict__ rois,
                         const float* __restrict__ probs,
                         const float* __restrict__ deltas,
                         const float* __restrict__ stdv,
                         float* __restrict__ score, int* __restrict__ cls,
                         int* __restrict__ valid, float* __restrict__ box) {
#pragma clang fp contract(off)
  int g = blockIdx.x * 4 + (threadIdx.x >> 6);
  if (g >= BB * NN) return;
  int lane = threadIdx.x & 63;
  int b = g / NN, n = g % NN;
  const float* pp = probs + ((size_t)b * NN + n) * CC;
  float best = -INFINITY;
  int bc = CC;
  for (int c = lane; c < CC; c += 64) {
    float p = pp[c];
    if (p > best) { best = p; bc = c; }   // per-lane stride keeps first max
  }
  // cross-lane argmax, first-occurrence tie-break (smaller class wins)
  for (int off = 32; off; off >>= 1) {
    float ob = __shfl_xor(best, off, 64);
    int oc = __shfl_xor(bc, off, 64);
    if (ob > best || (ob == best && oc < bc)) { best = ob; bc = oc; }
  }
  if (lane == 0) {
    int idx = b * NPAD + n;
    const float* r = rois + ((size_t)b * NN + n) * 4;
    const float* dd = deltas + (((size_t)b * NN + n) * CC + bc) * 4;
    float d0 = dd[0] * stdv[0], d1 = dd[1] * stdv[1];
    float d2 = dd[2] * stdv[2], d3 = dd[3] * stdv[3];
    float y1 = r[0], x1 = r[1], y2 = r[2], x2 = r[3];
    float h = y2 - y1, w = x2 - x1;
    float cy = y1 + 0.5f * h + d0 * h;
    float cx = x1 + 0.5f * w + d1 * w;
    h = h * (float)exp((double)d2);   // double path ~= correctly-rounded f32 exp
    w = w * (float)exp((double)d3);
    float ny1 = cy - 0.5f * h, nx1 = cx - 0.5f * w;
    float ny2 = cy + 0.5f * h, nx2 = cx + 0.5f * w;
    ny1 = fminf(fmaxf(ny1, 0.f), 1.f);
    nx1 = fminf(fmaxf(nx1, 0.f), 1.f);
    ny2 = fminf(fmaxf(ny2, 0.f), 1.f);
    nx2 = fminf(fmaxf(nx2, 0.f), 1.f);
    box[idx * 4 + 0] = ny1;
    box[idx * 4 + 1] = nx1;
    box[idx * 4 + 2] = ny2;
    box[idx * 4 + 3] = nx2;
    score[idx] = best;
    cls[idx] = bc;
    valid[idx] = (bc > 0 && best >= 0.05f) ? 1 : 0;
  }
}

// ---------------------------------------------------------------------------
// Kernel B: per-batch bitonic sort of 2048 packed keys in LDS.
// key = sortable(score_if_valid_else_-inf) << 32 | (0xFFFFFFFF - idx)
// Descending sort => score desc, index asc on ties (stable argsort of -score).
// ---------------------------------------------------------------------------
__global__ void k_sort(const float* __restrict__ score, const int* __restrict__ cls,
                       const int* __restrict__ valid, const float* __restrict__ box,
                       float* __restrict__ sscore, int* __restrict__ scls,
                       int* __restrict__ svalid, float* __restrict__ sbox) {
  __shared__ unsigned long long skey[NPAD];
  int b = blockIdx.x, tid = threadIdx.x;
  for (int t = tid; t < NPAD; t += 256) {
    float ks = -INFINITY;
    if (t < NN && valid[b * NPAD + t]) ks = score[b * NPAD + t];
    unsigned u = __float_as_uint(ks);
    u = (u & 0x80000000u) ? ~u : (u | 0x80000000u);
    skey[t] = ((unsigned long long)u << 32) | (0xFFFFFFFFu - (unsigned)t);
  }
  for (unsigned k = 2; k <= NPAD; k <<= 1) {
    for (unsigned j = k >> 1; j > 0; j >>= 1) {
      __syncthreads();
      for (unsigned i = tid; i < NPAD; i += 256) {
        unsigned l = i ^ j;
        if (l > i) {
          unsigned long long a = skey[i], c = skey[l];
          bool desc = ((i & k) == 0);
          if (desc ? (a < c) : (a > c)) { skey[i] = c; skey[l] = a; }
        }
      }
    }
  }
  __syncthreads();
  for (int t = tid; t < NPAD; t += 256) {
    unsigned idx = 0xFFFFFFFFu - (unsigned)(skey[t] & 0xFFFFFFFFu);
    int o = b * NPAD + t;
    if (idx < NN) {
      int ii = b * NPAD + (int)idx;
      sscore[o] = score[ii];
      scls[o] = cls[ii];
      svalid[o] = valid[ii];
      sbox[o * 4 + 0] = box[ii * 4 + 0];
      sbox[o * 4 + 1] = box[ii * 4 + 1];
      sbox[o * 4 + 2] = box[ii * 4 + 2];
      sbox[o * 4 + 3] = box[ii * 4 + 3];
    } else {
      sscore[o] = 0.f; scls[o] = 0; svalid[o] = 0;
      sbox[o * 4 + 0] = 0.f; sbox[o * 4 + 1] = 0.f;
      sbox[o * 4 + 2] = 0.f; sbox[o * 4 + 3] = 0.f;
    }
  }
}

// ---------------------------------------------------------------------------
// Kernel C: greedy sequential NMS, one wave per batch.
// Kept (offset) boxes in LDS (<=100). IoU on class-offset boxes reproduces the
// reference's fp32 rounding (and different classes give IoU=0 automatically).
// Early-exit at kept==100: output == top_k of kept == first 100 kept in order.
// Per-class count<100 is vacuous before total kept reaches 100.
// ---------------------------------------------------------------------------
__global__ void k_nms(const float* __restrict__ sscore, const int* __restrict__ scls,
                      const int* __restrict__ svalid, const float* __restrict__ sbox,
                      float* __restrict__ det) {
#pragma clang fp contract(off)
  __shared__ float kb[MAXI][4];
  __shared__ float karea[MAXI];
  int b = blockIdx.x, lane = threadIdx.x;
  int kept = 0;
  for (int i = 0; i < NN; i++) {
    int o = b * NPAD + i;
    if (!svalid[o]) break;  // sorted: all invalid are at the end
    int c = scls[o];
    float off = 2.0f * (float)c;
    float y1 = sbox[o * 4 + 0], x1 = sbox[o * 4 + 1];
    float y2 = sbox[o * 4 + 2], x2 = sbox[o * 4 + 3];
    float oy1 = y1 + off, ox1 = x1 + off, oy2 = y2 + off, ox2 = x2 + off;
    float area_i = (oy2 - oy1) * (ox2 - ox1);
    bool pred = false;
    for (int t = lane; t < kept; t += 64) {
      float ky1 = kb[t][0], kx1 = kb[t][1], ky2 = kb[t][2], kx2 = kb[t][3];
      float yy1 = fmaxf(oy1, ky1), xx1 = fmaxf(ox1, kx1);
      float yy2 = fminf(oy2, ky2), xx2 = fminf(ox2, kx2);
      float inter = fmaxf(yy2 - yy1, 0.f) * fmaxf(xx2 - xx1, 0.f);
      float uni = (area_i + karea[t]) - inter;
      float iou = inter / fmaxf(uni, 1e-12f);
      pred = pred || (iou > 0.3f);
    }
    if (__ballot(pred) == 0ULL) {
      if (lane == 0) {
        kb[kept][0] = oy1; kb[kept][1] = ox1;
        kb[kept][2] = oy2; kb[kept][3] = ox2;
        karea[kept] = area_i;
        float* dr = det + ((size_t)b * MAXI + kept) * 6;
        dr[0] = y1; dr[1] = x1; dr[2] = y2; dr[3] = x2;
        dr[4] = (float)c; dr[5] = sscore[o];
      }
      kept++;
      if (kept == MAXI) break;
      __syncthreads();  // make lane-0 LDS writes visible before next iteration
    }
  }
  // zero-fill remaining det rows (d_out is poisoned 0xAA)
  int rem = (MAXI - kept) * 6;
  float* dr0 = det + ((size_t)b * MAXI + kept) * 6;
  for (int t = lane; t < rem; t += 64) dr0[t] = 0.f;
}

// ---------------------------------------------------------------------------
// Kernel D: attention mask. One block per (batch, row, half-row of 256 px).
// Compact boxes covering this row's y into LDS, then per-pixel x tests.
// ---------------------------------------------------------------------------
__global__ void k_mask(const float* __restrict__ det, float* __restrict__ mask) {
  __shared__ float lx1[MAXI], lx2[MAXI];
  __shared__ int cnt;
  int x = blockIdx.x;
  int bw = x & 1;
  int h = (x >> 1) & (HH - 1);
  int b = x >> 10;
  int tid = threadIdx.x;
  if (tid == 0) cnt = 0;
  __syncthreads();
  float ys = ((float)h + 0.5f) * (1.0f / 512.0f);
  if (tid < MAXI) {
    const float* dr = det + ((size_t)b * MAXI + tid) * 6;
    float y1 = dr[0], bx1 = dr[1], y2 = dr[2], bx2 = dr[3];
    if (ys >= y1 && ys < y2) {  // zero (padded) boxes cover nothing
      int p = atomicAdd(&cnt, 1);
      lx1[p] = bx1; lx2[p] = bx2;
    }
  }
  __syncthreads();
  int w = bw * 256 + tid;
  float xs = ((float)w + 0.5f) * (1.0f / 512.0f);
  bool cov = false;
  int n = cnt;
  for (int t = 0; t < n; t++) cov = cov || (xs >= lx1[t] && xs < lx2[t]);
  mask[((size_t)b * HH + h) * WW + w] = cov ? 1.0f : 0.0f;
}

// ---------------------------------------------------------------------------
extern "C" void kernel_launch(void* const* d_in, const int* in_sizes, int n_in,
                              void* d_out, int out_size, void* d_ws, size_t ws_size,
                              hipStream_t stream) {
  const float* rois = (const float*)d_in[0];
  const float* probs = (const float*)d_in[1];
  const float* deltas = (const float*)d_in[2];
  const float* stdv = (const float*)d_in[3];
  float* out = (float*)d_out;
  float* det = out;                  // [8,100,6] = 4800 floats
  float* mask = out + BB * MAXI * 6; // [8,512,512]

  char* p = (char*)d_ws;
  float* score  = (float*)p; p += (size_t)BB * NPAD * 4;
  int*   cls    = (int*)p;   p += (size_t)BB * NPAD * 4;
  int*   valid  = (int*)p;   p += (size_t)BB * NPAD * 4;
  float* box    = (float*)p; p += (size_t)BB * NPAD * 16;
  float* sscore = (float*)p; p += (size_t)BB * NPAD * 4;
  int*   scls   = (int*)p;   p += (size_t)BB * NPAD * 4;
  int*   svalid = (int*)p;   p += (size_t)BB * NPAD * 4;
  float* sbox   = (float*)p; p += (size_t)BB * NPAD * 16;

  k_refine<<<(BB * NN) / 4, 256, 0, stream>>>(rois, probs, deltas, stdv,
                                              score, cls, valid, box);
  k_sort<<<BB, 256, 0, stream>>>(score, cls, valid, box, sscore, scls, svalid, sbox);
  k_nms<<<BB, 64, 0, stream>>>(sscore, scls, svalid, sbox, det);
  k_mask<<<BB * HH * (WW / 256), 256, 0, stream>>>(det, mask);
}

// Round 2
// 168.969 us; speedup vs baseline: 1.4044x; 1.4044x over previous
//
#include <hip/hip_runtime.h>
#include <math.h>

#define BB 8
#define NN 2000
#define CC 81
#define NPAD 2048
#define MAXI 100
#define HH 512
#define WW 512

// ---------------------------------------------------------------------------
// Kernel A: per-proposal class argmax, delta refine, validity.
// One wave (64 lanes) per proposal: coalesced prob reads, shuffle argmax.
// ---------------------------------------------------------------------------
__global__ void k_refine(const float* __restrict__ rois,
                         const float* __restrict__ probs,
                         const float* __restrict__ deltas,
                         const float* __restrict__ stdv,
                         float* __restrict__ score, int* __restrict__ cls,
                         int* __restrict__ valid, float* __restrict__ box) {
#pragma clang fp contract(off)
  int g = blockIdx.x * 4 + (threadIdx.x >> 6);
  if (g >= BB * NN) return;
  int lane = threadIdx.x & 63;
  int b = g / NN, n = g % NN;
  const float* pp = probs + ((size_t)b * NN + n) * CC;
  float best = -INFINITY;
  int bc = CC;
  for (int c = lane; c < CC; c += 64) {
    float p = pp[c];
    if (p > best) { best = p; bc = c; }   // per-lane stride keeps first max
  }
  // cross-lane argmax, first-occurrence tie-break (smaller class wins)
  for (int off = 32; off; off >>= 1) {
    float ob = __shfl_xor(best, off, 64);
    int oc = __shfl_xor(bc, off, 64);
    if (ob > best || (ob == best && oc < bc)) { best = ob; bc = oc; }
  }
  if (lane == 0) {
    int idx = b * NPAD + n;
    const float* r = rois + ((size_t)b * NN + n) * 4;
    const float* dd = deltas + (((size_t)b * NN + n) * CC + bc) * 4;
    float d0 = dd[0] * stdv[0], d1 = dd[1] * stdv[1];
    float d2 = dd[2] * stdv[2], d3 = dd[3] * stdv[3];
    float y1 = r[0], x1 = r[1], y2 = r[2], x2 = r[3];
    float h = y2 - y1, w = x2 - x1;
    float cy = y1 + 0.5f * h + d0 * h;
    float cx = x1 + 0.5f * w + d1 * w;
    h = h * (float)exp((double)d2);   // double path ~= correctly-rounded f32 exp
    w = w * (float)exp((double)d3);
    float ny1 = cy - 0.5f * h, nx1 = cx - 0.5f * w;
    float ny2 = cy + 0.5f * h, nx2 = cx + 0.5f * w;
    ny1 = fminf(fmaxf(ny1, 0.f), 1.f);
    nx1 = fminf(fmaxf(nx1, 0.f), 1.f);
    ny2 = fminf(fmaxf(ny2, 0.f), 1.f);
    nx2 = fminf(fmaxf(nx2, 0.f), 1.f);
    box[idx * 4 + 0] = ny1;
    box[idx * 4 + 1] = nx1;
    box[idx * 4 + 2] = ny2;
    box[idx * 4 + 3] = nx2;
    score[idx] = best;
    cls[idx] = bc;
    valid[idx] = (bc > 0 && best >= 0.05f) ? 1 : 0;
  }
}

// ---------------------------------------------------------------------------
// Kernel B (v2): rank sort. Keys are UNIQUE (index in low bits), so
// rank[i] = #{j : key[j] > key[i]} is a perfect permutation == stable
// argsort(score desc, idx asc). 8 blocks per batch, 1 element per thread;
// all 2048 keys in LDS; every lane reads the same key per iteration ->
// broadcast, conflict-free. One barrier total (vs 66 bitonic passes).
// ---------------------------------------------------------------------------
__global__ void k_rank(const float* __restrict__ score, const int* __restrict__ cls,
                       const int* __restrict__ valid, const float* __restrict__ box,
                       float* __restrict__ sscore, int* __restrict__ scls,
                       int* __restrict__ svalid, float* __restrict__ sbox) {
  __shared__ unsigned long long skey[NPAD];
  int b = blockIdx.x >> 3, part = blockIdx.x & 7, tid = threadIdx.x;
  for (int t = tid; t < NPAD; t += 256) {
    float ks = -INFINITY;
    if (t < NN && valid[b * NPAD + t]) ks = score[b * NPAD + t];
    unsigned u = __float_as_uint(ks);
    u = (u & 0x80000000u) ? ~u : (u | 0x80000000u);
    skey[t] = ((unsigned long long)u << 32) | (0xFFFFFFFFu - (unsigned)t);
  }
  __syncthreads();
  int me = part * 256 + tid;
  unsigned long long myk = skey[me];
  int rank = 0;
#pragma unroll 8
  for (int j = 0; j < NPAD; j++) rank += (skey[j] > myk) ? 1 : 0;
  int o = b * NPAD + rank;
  if (me < NN) {
    int ii = b * NPAD + me;
    sscore[o] = score[ii];
    scls[o] = cls[ii];
    svalid[o] = valid[ii];
    ((float4*)sbox)[o] = ((const float4*)box)[ii];
  } else {
    sscore[o] = 0.f; scls[o] = 0; svalid[o] = 0;
    ((float4*)sbox)[o] = make_float4(0.f, 0.f, 0.f, 0.f);
  }
}

// ---------------------------------------------------------------------------
// Kernel C (v2): greedy sequential NMS, one wave per batch.
// Candidates prefetched 64 at a time (coalesced float4/lane), broadcast via
// shuffles. Kept set lives in REGISTERS: kept index t==lane in slot0,
// t==64+lane in slot1; the owner lane captures the already-broadcast values,
// so no LDS and no barriers at all. Early-exit at kept==100 (== top_k of kept
// since the list is score-sorted). Per-class count<100 is vacuous before
// total kept reaches 100; cross-class IoU is 0 by the class-offset trick.
// ---------------------------------------------------------------------------
__global__ void k_nms(const float* __restrict__ sscore, const int* __restrict__ scls,
                      const int* __restrict__ svalid, const float* __restrict__ sbox,
                      float* __restrict__ det) {
#pragma clang fp contract(off)
  int b = blockIdx.x, lane = threadIdx.x;
  int kept = 0;
  bool done = false;
  // register-resident kept boxes (offset coords) + area
  float k0y1 = 0.f, k0x1 = 0.f, k0y2 = 0.f, k0x2 = 0.f, k0a = 0.f;
  float k1y1 = 0.f, k1x1 = 0.f, k1y2 = 0.f, k1x2 = 0.f, k1a = 0.f;
  for (int base = 0; base < NN && !done; base += 64) {
    int o = b * NPAD + base + lane;
    float4 bx = ((const float4*)sbox)[o];
    int lv = svalid[o];
    int lc = scls[o];
    float lsc = sscore[o];
    int lim = (NN - base < 64) ? (NN - base) : 64;
    for (int j = 0; j < lim; j++) {
      int v = __shfl(lv, j, 64);
      if (!v) { done = true; break; }   // sorted: all invalid at the end
      float y1 = __shfl(bx.x, j, 64);
      float x1 = __shfl(bx.y, j, 64);
      float y2 = __shfl(bx.z, j, 64);
      float x2 = __shfl(bx.w, j, 64);
      int c = __shfl(lc, j, 64);
      float off = 2.0f * (float)c;
      float oy1 = y1 + off, ox1 = x1 + off, oy2 = y2 + off, ox2 = x2 + off;
      float area_i = (oy2 - oy1) * (ox2 - ox1);
      bool pred = false;
      if (lane < kept) {
        float yy1 = fmaxf(oy1, k0y1), xx1 = fmaxf(ox1, k0x1);
        float yy2 = fminf(oy2, k0y2), xx2 = fminf(ox2, k0x2);
        float inter = fmaxf(yy2 - yy1, 0.f) * fmaxf(xx2 - xx1, 0.f);
        float uni = (area_i + k0a) - inter;
        pred = (inter / fmaxf(uni, 1e-12f)) > 0.3f;
      }
      if (64 + lane < kept) {
        float yy1 = fmaxf(oy1, k1y1), xx1 = fmaxf(ox1, k1x1);
        float yy2 = fminf(oy2, k1y2), xx2 = fminf(ox2, k1x2);
        float inter = fmaxf(yy2 - yy1, 0.f) * fmaxf(xx2 - xx1, 0.f);
        float uni = (area_i + k1a) - inter;
        pred = pred || ((inter / fmaxf(uni, 1e-12f)) > 0.3f);
      }
      if (__ballot(pred) == 0ULL) {            // wave-uniform accept
        if (kept < 64) {
          if (lane == kept) { k0y1 = oy1; k0x1 = ox1; k0y2 = oy2; k0x2 = ox2; k0a = area_i; }
        } else {
          if (lane == kept - 64) { k1y1 = oy1; k1x1 = ox1; k1y2 = oy2; k1x2 = ox2; k1a = area_i; }
        }
        float sc = __shfl(lsc, j, 64);
        if (lane == 0) {
          float* dr = det + ((size_t)b * MAXI + kept) * 6;
          dr[0] = y1; dr[1] = x1; dr[2] = y2; dr[3] = x2;
          dr[4] = (float)c; dr[5] = sc;
        }
        kept++;
        if (kept == MAXI) { done = true; break; }
      }
    }
  }
  // zero-fill remaining det rows (d_out is poisoned 0xAA)
  int rem = (MAXI - kept) * 6;
  float* dr0 = det + ((size_t)b * MAXI + kept) * 6;
  for (int t = lane; t < rem; t += 64) dr0[t] = 0.f;
}

// ---------------------------------------------------------------------------
// Kernel D: attention mask. One block per (batch, row, half-row of 256 px).
// Compact boxes covering this row's y into LDS, then per-pixel x tests.
// ---------------------------------------------------------------------------
__global__ void k_mask(const float* __restrict__ det, float* __restrict__ mask) {
  __shared__ float lx1[MAXI], lx2[MAXI];
  __shared__ int cnt;
  int x = blockIdx.x;
  int bw = x & 1;
  int h = (x >> 1) & (HH - 1);
  int b = x >> 10;
  int tid = threadIdx.x;
  if (tid == 0) cnt = 0;
  __syncthreads();
  float ys = ((float)h + 0.5f) * (1.0f / 512.0f);
  if (tid < MAXI) {
    const float* dr = det + ((size_t)b * MAXI + tid) * 6;
    float y1 = dr[0], bx1 = dr[1], y2 = dr[2], bx2 = dr[3];
    if (ys >= y1 && ys < y2) {  // zero (padded) boxes cover nothing
      int p = atomicAdd(&cnt, 1);
      lx1[p] = bx1; lx2[p] = bx2;
    }
  }
  __syncthreads();
  int w = bw * 256 + tid;
  float xs = ((float)w + 0.5f) * (1.0f / 512.0f);
  bool cov = false;
  int n = cnt;
  for (int t = 0; t < n; t++) cov = cov || (xs >= lx1[t] && xs < lx2[t]);
  mask[((size_t)b * HH + h) * WW + w] = cov ? 1.0f : 0.0f;
}

// ---------------------------------------------------------------------------
extern "C" void kernel_launch(void* const* d_in, const int* in_sizes, int n_in,
                              void* d_out, int out_size, void* d_ws, size_t ws_size,
                              hipStream_t stream) {
  const float* rois = (const float*)d_in[0];
  const float* probs = (const float*)d_in[1];
  const float* deltas = (const float*)d_in[2];
  const float* stdv = (const float*)d_in[3];
  float* out = (float*)d_out;
  float* det = out;                  // [8,100,6] = 4800 floats
  float* mask = out + BB * MAXI * 6; // [8,512,512]

  char* p = (char*)d_ws;
  float* score  = (float*)p; p += (size_t)BB * NPAD * 4;
  int*   cls    = (int*)p;   p += (size_t)BB * NPAD * 4;
  int*   valid  = (int*)p;   p += (size_t)BB * NPAD * 4;
  float* box    = (float*)p; p += (size_t)BB * NPAD * 16;
  float* sscore = (float*)p; p += (size_t)BB * NPAD * 4;
  int*   scls   = (int*)p;   p += (size_t)BB * NPAD * 4;
  int*   svalid = (int*)p;   p += (size_t)BB * NPAD * 4;
  float* sbox   = (float*)p; p += (size_t)BB * NPAD * 16;

  k_refine<<<(BB * NN) / 4, 256, 0, stream>>>(rois, probs, deltas, stdv,
                                              score, cls, valid, box);
  k_rank<<<BB * 8, 256, 0, stream>>>(score, cls, valid, box, sscore, scls, svalid, sbox);
  k_nms<<<BB, 64, 0, stream>>>(sscore, scls, svalid, sbox, det);
  k_mask<<<BB * HH * (WW / 256), 256, 0, stream>>>(det, mask);
}